// Round 5
// baseline (1338.340 us; speedup 1.0000x reference)
//
#include <hip/hip_runtime.h>

#define D 128

typedef short v8s __attribute__((ext_vector_type(8)));
typedef float v4f __attribute__((ext_vector_type(4)));

// fp32 -> bf16 hi/lo split: f ~= hi + lo, |err| ~ 2^-17 * |f|
__device__ __forceinline__ void f2hl(float f, unsigned short& h, unsigned short& l) {
    unsigned int u = __float_as_uint(f);
    unsigned int hu = u & 0xffff0000u;
    float lf = f - __uint_as_float(hu);          // exact
    h = (unsigned short)(hu >> 16);
    l = (unsigned short)((__float_as_uint(lf) + 0x8000u) >> 16);  // round
}

// permuted column position for a 4-aligned k chunk (MFMA A-frag contiguous layout)
// k = 4g + (e&3) + 16*(e>>2)  <->  p = 8g + e   (within each 32-wide k block)
__device__ __forceinline__ int permc(int c) {
    return (c & ~31) + ((c & 12) << 1) + ((c & 16) >> 2);
}

// ---------------- preprocessing (unchanged) ----------------

__global__ void k_count(const int* __restrict__ dst, int* __restrict__ deg, int E) {
    int e = blockIdx.x * 256 + threadIdx.x;
    if (e < E) atomicAdd(&deg[dst[e]], 1);
}

__global__ __launch_bounds__(256) void k_blocksum(const int* __restrict__ deg,
                                                  int* __restrict__ bsums, int N) {
    __shared__ int s[256];
    int base = blockIdx.x * 1024 + threadIdx.x * 4;
    int v = 0;
#pragma unroll
    for (int j = 0; j < 4; ++j) { int i = base + j; if (i < N) v += deg[i]; }
    s[threadIdx.x] = v;
    __syncthreads();
    for (int off = 128; off > 0; off >>= 1) {
        if (threadIdx.x < off) s[threadIdx.x] += s[threadIdx.x + off];
        __syncthreads();
    }
    if (threadIdx.x == 0) bsums[blockIdx.x] = s[0];
}

__global__ __launch_bounds__(256) void k_scanbsums(int* __restrict__ bsums, int NB) {
    __shared__ int s[256];
    __shared__ int carry;
    int t = threadIdx.x;
    if (t == 0) carry = 0;
    __syncthreads();
    for (int base = 0; base < NB; base += 256) {
        int i = base + t;
        int v = (i < NB) ? bsums[i] : 0;
        s[t] = v;
        __syncthreads();
        for (int off = 1; off < 256; off <<= 1) {
            int x = (t >= off) ? s[t - off] : 0;
            __syncthreads();
            s[t] += x;
            __syncthreads();
        }
        if (i < NB) bsums[i] = carry + s[t] - v;   // exclusive
        __syncthreads();
        if (t == 0) carry += s[255];
        __syncthreads();
    }
}

__global__ __launch_bounds__(256) void k_scan2(const int* __restrict__ deg,
                                               const int* __restrict__ bsums,
                                               int* __restrict__ rowst,
                                               float* __restrict__ dinv, int N) {
    __shared__ int s[256];
    int t = threadIdx.x;
    int base = blockIdx.x * 1024 + t * 4;
    int v[4];
#pragma unroll
    for (int j = 0; j < 4; ++j) { int i = base + j; v[j] = (i < N) ? deg[i] : 0; }
    int tsum = v[0] + v[1] + v[2] + v[3];
    s[t] = tsum;
    __syncthreads();
    for (int off = 1; off < 256; off <<= 1) {
        int x = (t >= off) ? s[t - off] : 0;
        __syncthreads();
        s[t] += x;
        __syncthreads();
    }
    int run = s[t] - tsum + bsums[blockIdx.x];
#pragma unroll
    for (int j = 0; j < 4; ++j) {
        int i = base + j;
        if (i < N) {
            rowst[i] = run;
            dinv[i] = rsqrtf((float)(v[j] + 1));   // +1 for self-loop
        }
        run += v[j];
    }
}

__global__ void k_fill(const int* __restrict__ src, const int* __restrict__ dst,
                       const int* __restrict__ rowst, int* __restrict__ cursor,
                       const float* __restrict__ dinv, int2* __restrict__ csr, int E) {
    int e = blockIdx.x * 256 + threadIdx.x;
    if (e >= E) return;
    int s = src[e], d = dst[e];
    int p = rowst[d] + atomicAdd(&cursor[d], 1);
    csr[p] = make_int2(s, __float_as_int(dinv[s] * dinv[d]));
}

// ---------------- weight fragment packing ----------------

// Ws[9][128][128] fp32 -> per-lane MFMA B fragments, hi/lo bf16:
// wf[((l*4+ks)*8+nt)*64 + lane][8 words]: words 0-3 = hi frag, 4-7 = lo frag
__global__ __launch_bounds__(64) void k_wconv(const float* __restrict__ Ws,
                                              unsigned int* __restrict__ wf) {
    int b = blockIdx.x;              // l*32 + ks*8 + nt
    int l = b >> 5, ks = (b >> 3) & 3, nt = b & 7;
    int lane = threadIdx.x;
    int g = lane >> 4, c = (lane & 15) + nt * 16;
    const float* W = Ws + (size_t)l * D * D;
    unsigned int hw[4], lw[4];
#pragma unroll
    for (int w = 0; w < 4; ++w) {
        unsigned short hs[2], ls[2];
#pragma unroll
        for (int j = 0; j < 2; ++j) {
            int e = 2 * w + j;
            int k = ks * 32 + 4 * g + (e & 3) + 16 * (e >> 2);
            f2hl(W[k * D + c], hs[j], ls[j]);
        }
        hw[w] = (unsigned int)hs[0] | ((unsigned int)hs[1] << 16);
        lw[w] = (unsigned int)ls[0] | ((unsigned int)ls[1] << 16);
    }
    unsigned int* dstp = wf + ((size_t)((l * 4 + ks) * 8 + nt) * 64 + lane) * 8;
    *(uint4*)dstp = make_uint4(hw[0], hw[1], hw[2], hw[3]);
    *(uint4*)(dstp + 4) = make_uint4(lw[0], lw[1], lw[2], lw[3]);
}

// Wo[128,16] fp32 -> wof[(ks*64 + lane)*8]: hi frag words 0-3, lo words 4-7
__global__ __launch_bounds__(64) void k_woconv(const float* __restrict__ Wo,
                                               unsigned int* __restrict__ wof) {
    int ks = blockIdx.x;
    int lane = threadIdx.x;
    int g = lane >> 4, c = lane & 15;
    unsigned int hw[4], lw[4];
#pragma unroll
    for (int w = 0; w < 4; ++w) {
        unsigned short hs[2], ls[2];
#pragma unroll
        for (int j = 0; j < 2; ++j) {
            int e = 2 * w + j;
            int k = ks * 32 + 4 * g + (e & 3) + 16 * (e >> 2);
            f2hl(Wo[k * 16 + c], hs[j], ls[j]);
        }
        hw[w] = (unsigned int)hs[0] | ((unsigned int)hs[1] << 16);
        lw[w] = (unsigned int)ls[0] | ((unsigned int)ls[1] << 16);
    }
    unsigned int* dstp = wof + ((size_t)(ks * 64 + lane)) * 8;
    *(uint4*)dstp = make_uint4(hw[0], hw[1], hw[2], hw[3]);
    *(uint4*)(dstp + 4) = make_uint4(lw[0], lw[1], lw[2], lw[3]);
}

// ---------------- fused layer: hout = act( (A_norm . hin) @ W + b ) ----------------
// Persistent blocks pop ROWS-node tiles from an atomic queue.
// Phase 1 (branch-free interleaved gather): each 32-lane group owns NPG nodes and
//   walks their edge lists CONCURRENTLY, issuing NPG*JST=8 independent row loads per
//   iteration with clamped indices (exhausted nodes re-load a resident line, w=0).
// Phase 2: 4 waves cover ROWS x (NTT*16) outputs via split-bf16 MFMA, bias(+ReLU).

template <int ROWS, int NTT, int RELU, int OSTRIDE>
__global__ __launch_bounds__(256) void k_fused(const float* __restrict__ hin,
                                               const int2* __restrict__ csr,
                                               const int* __restrict__ rowst,
                                               const int* __restrict__ deg,
                                               const float* __restrict__ dinv,
                                               const unsigned int* __restrict__ wf,
                                               const float* __restrict__ bias,
                                               float* __restrict__ hout, int N,
                                               int* __restrict__ qctr, int ntiles) {
    __shared__ float sT[ROWS * 128];
    __shared__ int s_tile;

    const int gp = threadIdx.x >> 5;
    const int l32 = threadIdx.x & 31;
    const int c = l32 << 2;
    const int p0 = permc(c);

    constexpr int NPG = ROWS / 8;        // nodes per 32-lane group
    constexpr int JST = 8 / NPG;         // edges per node per iteration

    for (;;) {
        if (threadIdx.x == 0) s_tile = atomicAdd(qctr, 1);
        __syncthreads();
        const int tile = s_tile;
        if (tile >= ntiles) break;
        const int nb = tile * ROWS;

        // ---- phase 1: interleaved gather/aggregate into registers ----
        {
            const int sb = gp * NPG;
            float4 acc[NPG];
            int eoff[NPG], rem[NPG];
            int mx = 0;
#pragma unroll
            for (int jj = 0; jj < NPG; ++jj) {
                int node = nb + sb + jj;
                bool ok = (node < N);
                float4 a = make_float4(0.f, 0.f, 0.f, 0.f);
                if (ok) {
                    float di = dinv[node];
                    float s2 = di * di;
                    float4 t0 = *(const float4*)&hin[(size_t)node * D + c];
                    a.x = s2 * t0.x; a.y = s2 * t0.y;
                    a.z = s2 * t0.z; a.w = s2 * t0.w;
                }
                acc[jj] = a;
                eoff[jj] = ok ? rowst[node] : 0;
                rem[jj] = ok ? deg[node] : 0;
                mx = (rem[jj] > mx) ? rem[jj] : mx;
            }

            for (int j = 0; j < mx; j += JST) {
                int2 ed[NPG][JST];
#pragma unroll
                for (int jj = 0; jj < NPG; ++jj)
#pragma unroll
                    for (int u = 0; u < JST; ++u) {
                        int idx = j + u;
                        int last = rem[jj] - 1;
                        idx = (idx < last) ? idx : last;
                        idx = (idx < 0) ? 0 : idx;
                        ed[jj][u] = csr[eoff[jj] + idx];
                    }
                float4 r[NPG][JST];
#pragma unroll
                for (int jj = 0; jj < NPG; ++jj)
#pragma unroll
                    for (int u = 0; u < JST; ++u)
                        r[jj][u] = *(const float4*)&hin[(size_t)ed[jj][u].x * D + c];
#pragma unroll
                for (int jj = 0; jj < NPG; ++jj)
#pragma unroll
                    for (int u = 0; u < JST; ++u) {
                        float w_ = ((j + u) < rem[jj]) ? __int_as_float(ed[jj][u].y) : 0.f;
                        acc[jj].x = fmaf(w_, r[jj][u].x, acc[jj].x);
                        acc[jj].y = fmaf(w_, r[jj][u].y, acc[jj].y);
                        acc[jj].z = fmaf(w_, r[jj][u].z, acc[jj].z);
                        acc[jj].w = fmaf(w_, r[jj][u].w, acc[jj].w);
                    }
            }

#pragma unroll
            for (int jj = 0; jj < NPG; ++jj) {
                int s = sb + jj;
                *(float4*)&sT[s * 128 + (p0 ^ ((s & 7) << 2))] = acc[jj];
            }
        }
        __syncthreads();

        // ---- phase 2: split-bf16 MFMA ----
        {
            constexpr int WR = ROWS / 16;        // row tiles
            constexpr int CG = 4 / WR;           // col groups (waves per row tile)
            constexpr int NTW = NTT / CG;        // col tiles per wave
            const int w = threadIdx.x >> 6;
            const int lane = threadIdx.x & 63;
            const int q = lane & 15, g = lane >> 4;
            const int rtile = w % WR;
            const int cg = w / WR;
            const int rloc = rtile * 16 + q;
            const int sw = (q & 7) << 2;

            v4f acc[NTW];
#pragma unroll
            for (int nt = 0; nt < NTW; ++nt) acc[nt] = (v4f)0.f;

            const float* rp = &sT[rloc * 128];

#pragma unroll
            for (int ks = 0; ks < 4; ++ks) {
                int o = ks * 32 + g * 8;
                float4 fa = *(const float4*)&rp[o ^ sw];
                float4 fb = *(const float4*)&rp[(o + 4) ^ sw];
                v8s ah, al;
                {
                    unsigned short h_, l_;
                    f2hl(fa.x, h_, l_); ah[0] = (short)h_; al[0] = (short)l_;
                    f2hl(fa.y, h_, l_); ah[1] = (short)h_; al[1] = (short)l_;
                    f2hl(fa.z, h_, l_); ah[2] = (short)h_; al[2] = (short)l_;
                    f2hl(fa.w, h_, l_); ah[3] = (short)h_; al[3] = (short)l_;
                    f2hl(fb.x, h_, l_); ah[4] = (short)h_; al[4] = (short)l_;
                    f2hl(fb.y, h_, l_); ah[5] = (short)h_; al[5] = (short)l_;
                    f2hl(fb.z, h_, l_); ah[6] = (short)h_; al[6] = (short)l_;
                    f2hl(fb.w, h_, l_); ah[7] = (short)h_; al[7] = (short)l_;
                }
                const unsigned int* wk = wf + ((size_t)(ks * NTT + cg * NTW) * 64 + lane) * 8;
#pragma unroll
                for (int nt = 0; nt < NTW; ++nt) {
                    v8s wh = *(const v8s*)(wk + nt * 512);
                    v8s wl = *(const v8s*)(wk + nt * 512 + 4);
                    acc[nt] = __builtin_amdgcn_mfma_f32_16x16x32_bf16(ah, wh, acc[nt], 0, 0, 0);
                    acc[nt] = __builtin_amdgcn_mfma_f32_16x16x32_bf16(al, wh, acc[nt], 0, 0, 0);
                    acc[nt] = __builtin_amdgcn_mfma_f32_16x16x32_bf16(ah, wl, acc[nt], 0, 0, 0);
                }
            }

            // epilogue: bias (+ReLU), store. C/D layout: col = q, row = 4g + i
            const int growb = nb + rtile * 16 + 4 * g;
#pragma unroll
            for (int nt = 0; nt < NTW; ++nt) {
                int col = (cg * NTW + nt) * 16 + q;
                float bv = bias[col];
#pragma unroll
                for (int i = 0; i < 4; ++i) {
                    int grow = growb + i;
                    if (grow < N) {
                        float v = acc[nt][i] + bv;
                        if (RELU) v = fmaxf(v, 0.f);
                        hout[(size_t)grow * OSTRIDE + col] = v;
                    }
                }
            }
        }
        __syncthreads();   // protect sT and s_tile for next tile
    }
}

// ---------------- launch ----------------

extern "C" void kernel_launch(void* const* d_in, const int* in_sizes, int n_in,
                              void* d_out, int out_size, void* d_ws, size_t ws_size,
                              hipStream_t stream) {
    const float* x  = (const float*)d_in[0];
    const int*   ei = (const int*)d_in[1];
    const float* Ws = (const float*)d_in[2];
    const float* bs = (const float*)d_in[3];
    const float* Wo = (const float*)d_in[4];
    const float* bo = (const float*)d_in[5];
    float* out = (float*)d_out;

    const int N = in_sizes[0] / D;     // 100000
    const int E = in_sizes[1] / 2;     // 600000
    const int* src = ei;
    const int* dst = ei + E;

    // workspace layout (~109.4 MB)
    float* H0     = (float*)d_ws;                     // N*128 fp32 ping
    float* H1     = H0 + (size_t)N * D;               // N*128 fp32 pong
    int*   deg    = (int*)(H1 + (size_t)N * D);
    int*   cursor = deg + N;
    int*   rowst  = cursor + N;
    float* dinv   = (float*)(rowst + N);
    int*   bsums  = (int*)(dinv + N);
    int2*  csr    = (int2*)(bsums + 1024);
    unsigned int* wfrag  = (unsigned int*)(csr + E);  // 9 * 16384 uints (576 KB)
    unsigned int* wofrag = wfrag + 9 * 16384;         // 2048 uints (8 KB)
    int*   qctr   = (int*)(wofrag + 2048);            // 16 ints (tile queues)

    const int NB = (N + 1023) / 1024;

    hipMemsetAsync(deg, 0, (size_t)2 * N * sizeof(int), stream);  // deg + cursor
    hipMemsetAsync(qctr, 0, 16 * sizeof(int), stream);
    k_count<<<(E + 255) / 256, 256, 0, stream>>>(dst, deg, E);
    k_blocksum<<<NB, 256, 0, stream>>>(deg, bsums, N);
    k_scanbsums<<<1, 256, 0, stream>>>(bsums, NB);
    k_scan2<<<NB, 256, 0, stream>>>(deg, bsums, rowst, dinv, N);
    k_fill<<<(E + 255) / 256, 256, 0, stream>>>(src, dst, rowst, cursor, dinv, csr, E);

    k_wconv<<<288, 64, 0, stream>>>(Ws, wfrag);
    k_woconv<<<4, 64, 0, stream>>>(Wo, wofrag);

    const float* hin = x;
    float* hout = H0;
    const int ntiles32 = (N + 31) / 32;
    for (int l = 0; l < 9; ++l) {
        int grid = (ntiles32 < 2048) ? ntiles32 : 2048;
        k_fused<32, 8, 1, 128><<<grid, 256, 0, stream>>>(hin, csr, rowst, deg, dinv,
                                                         wfrag + (size_t)l * 16384,
                                                         bs + (size_t)l * D, hout, N,
                                                         qctr + l, ntiles32);
        hin = hout;
        hout = (hout == H0) ? H1 : H0;
    }
    const int ntiles64 = (N + 63) / 64;
    int gridh = (ntiles64 < 1024) ? ntiles64 : 1024;
    k_fused<64, 1, 0, 16><<<gridh, 256, 0, stream>>>(hin, csr, rowst, deg, dinv,
                                                     wofrag, bo, out, N,
                                                     qctr + 9, ntiles64);
}

// Round 6
// 886.568 us; speedup vs baseline: 1.5096x; 1.5096x over previous
//
#include <hip/hip_runtime.h>

#define D 128

typedef short v8s __attribute__((ext_vector_type(8)));
typedef float v4f __attribute__((ext_vector_type(4)));

// fp32 -> bf16 hi/lo split: f ~= hi + lo, |err| ~ 2^-17 * |f|
__device__ __forceinline__ void f2hl(float f, unsigned short& h, unsigned short& l) {
    unsigned int u = __float_as_uint(f);
    unsigned int hu = u & 0xffff0000u;
    float lf = f - __uint_as_float(hu);          // exact
    h = (unsigned short)(hu >> 16);
    l = (unsigned short)((__float_as_uint(lf) + 0x8000u) >> 16);  // round
}

// permuted column position for a 4-aligned k chunk (MFMA A-frag contiguous layout)
// k = 4g + (e&3) + 16*(e>>2)  <->  p = 8g + e   (within each 32-wide k block)
__device__ __forceinline__ int permc(int c) {
    return (c & ~31) + ((c & 12) << 1) + ((c & 16) >> 2);
}

// ---------------- preprocessing (unchanged) ----------------

__global__ void k_count(const int* __restrict__ dst, int* __restrict__ deg, int E) {
    int e = blockIdx.x * 256 + threadIdx.x;
    if (e < E) atomicAdd(&deg[dst[e]], 1);
}

__global__ __launch_bounds__(256) void k_blocksum(const int* __restrict__ deg,
                                                  int* __restrict__ bsums, int N) {
    __shared__ int s[256];
    int base = blockIdx.x * 1024 + threadIdx.x * 4;
    int v = 0;
#pragma unroll
    for (int j = 0; j < 4; ++j) { int i = base + j; if (i < N) v += deg[i]; }
    s[threadIdx.x] = v;
    __syncthreads();
    for (int off = 128; off > 0; off >>= 1) {
        if (threadIdx.x < off) s[threadIdx.x] += s[threadIdx.x + off];
        __syncthreads();
    }
    if (threadIdx.x == 0) bsums[blockIdx.x] = s[0];
}

__global__ __launch_bounds__(256) void k_scanbsums(int* __restrict__ bsums, int NB) {
    __shared__ int s[256];
    __shared__ int carry;
    int t = threadIdx.x;
    if (t == 0) carry = 0;
    __syncthreads();
    for (int base = 0; base < NB; base += 256) {
        int i = base + t;
        int v = (i < NB) ? bsums[i] : 0;
        s[t] = v;
        __syncthreads();
        for (int off = 1; off < 256; off <<= 1) {
            int x = (t >= off) ? s[t - off] : 0;
            __syncthreads();
            s[t] += x;
            __syncthreads();
        }
        if (i < NB) bsums[i] = carry + s[t] - v;   // exclusive
        __syncthreads();
        if (t == 0) carry += s[255];
        __syncthreads();
    }
}

__global__ __launch_bounds__(256) void k_scan2(const int* __restrict__ deg,
                                               const int* __restrict__ bsums,
                                               int* __restrict__ rowst,
                                               float* __restrict__ dinv, int N) {
    __shared__ int s[256];
    int t = threadIdx.x;
    int base = blockIdx.x * 1024 + t * 4;
    int v[4];
#pragma unroll
    for (int j = 0; j < 4; ++j) { int i = base + j; v[j] = (i < N) ? deg[i] : 0; }
    int tsum = v[0] + v[1] + v[2] + v[3];
    s[t] = tsum;
    __syncthreads();
    for (int off = 1; off < 256; off <<= 1) {
        int x = (t >= off) ? s[t - off] : 0;
        __syncthreads();
        s[t] += x;
        __syncthreads();
    }
    int run = s[t] - tsum + bsums[blockIdx.x];
#pragma unroll
    for (int j = 0; j < 4; ++j) {
        int i = base + j;
        if (i < N) {
            rowst[i] = run;
            dinv[i] = rsqrtf((float)(v[j] + 1));   // +1 for self-loop
        }
        run += v[j];
    }
}

__global__ void k_fill(const int* __restrict__ src, const int* __restrict__ dst,
                       const int* __restrict__ rowst, int* __restrict__ cursor,
                       const float* __restrict__ dinv, int2* __restrict__ csr, int E) {
    int e = blockIdx.x * 256 + threadIdx.x;
    if (e >= E) return;
    int s = src[e], d = dst[e];
    int p = rowst[d] + atomicAdd(&cursor[d], 1);
    csr[p] = make_int2(s, __float_as_int(dinv[s] * dinv[d]));
}

// ---------------- weight fragment packing ----------------

// Ws[9][128][128] fp32 -> per-lane MFMA B fragments, hi/lo bf16:
// wf[((l*4+ks)*8+nt)*64 + lane][8 words]: words 0-3 = hi frag, 4-7 = lo frag
__global__ __launch_bounds__(64) void k_wconv(const float* __restrict__ Ws,
                                              unsigned int* __restrict__ wf) {
    int b = blockIdx.x;              // l*32 + ks*8 + nt
    int l = b >> 5, ks = (b >> 3) & 3, nt = b & 7;
    int lane = threadIdx.x;
    int g = lane >> 4, c = (lane & 15) + nt * 16;
    const float* W = Ws + (size_t)l * D * D;
    unsigned int hw[4], lw[4];
#pragma unroll
    for (int w = 0; w < 4; ++w) {
        unsigned short hs[2], ls[2];
#pragma unroll
        for (int j = 0; j < 2; ++j) {
            int e = 2 * w + j;
            int k = ks * 32 + 4 * g + (e & 3) + 16 * (e >> 2);
            f2hl(W[k * D + c], hs[j], ls[j]);
        }
        hw[w] = (unsigned int)hs[0] | ((unsigned int)hs[1] << 16);
        lw[w] = (unsigned int)ls[0] | ((unsigned int)ls[1] << 16);
    }
    unsigned int* dstp = wf + ((size_t)((l * 4 + ks) * 8 + nt) * 64 + lane) * 8;
    *(uint4*)dstp = make_uint4(hw[0], hw[1], hw[2], hw[3]);
    *(uint4*)(dstp + 4) = make_uint4(lw[0], lw[1], lw[2], lw[3]);
}

// Wo[128,16] fp32 -> wof[(ks*64 + lane)*8]: hi frag words 0-3, lo words 4-7
__global__ __launch_bounds__(64) void k_woconv(const float* __restrict__ Wo,
                                               unsigned int* __restrict__ wof) {
    int ks = blockIdx.x;
    int lane = threadIdx.x;
    int g = lane >> 4, c = lane & 15;
    unsigned int hw[4], lw[4];
#pragma unroll
    for (int w = 0; w < 4; ++w) {
        unsigned short hs[2], ls[2];
#pragma unroll
        for (int j = 0; j < 2; ++j) {
            int e = 2 * w + j;
            int k = ks * 32 + 4 * g + (e & 3) + 16 * (e >> 2);
            f2hl(Wo[k * 16 + c], hs[j], ls[j]);
        }
        hw[w] = (unsigned int)hs[0] | ((unsigned int)hs[1] << 16);
        lw[w] = (unsigned int)ls[0] | ((unsigned int)ls[1] << 16);
    }
    unsigned int* dstp = wof + ((size_t)(ks * 64 + lane)) * 8;
    *(uint4*)dstp = make_uint4(hw[0], hw[1], hw[2], hw[3]);
    *(uint4*)(dstp + 4) = make_uint4(lw[0], lw[1], lw[2], lw[3]);
}

// ---------------- fused layer: hout = act( (A_norm . hin) @ W + b ) ----------------
// ROWS-node tile per THREADS-thread block (round-3 structure, smaller blocks).
// Phase 1: THREADS/32 groups of 32 lanes gather/aggregate ROWS/(THREADS/32) nodes
//          each into LDS (fp32), MFMA-permuted + XOR-bank-swizzled. Sequential
//          per-node walk with unroll-4 load pipeline (best measured ILP).
// Phase 2: waves cover ROWS x (NTT*16) outputs via split-bf16 MFMA, bias(+ReLU).
// Hidden: THREADS=128, ROWS=16 -> 8.2 KB LDS, 16 blocks/CU target (32 waves).

template <int THREADS, int ROWS, int NTT, int RELU, int OSTRIDE>
__global__ __launch_bounds__(THREADS, 8) void k_fused(const float* __restrict__ hin,
                                                      const int2* __restrict__ csr,
                                                      const int* __restrict__ rowst,
                                                      const int* __restrict__ deg,
                                                      const float* __restrict__ dinv,
                                                      const unsigned int* __restrict__ wf,
                                                      const float* __restrict__ bias,
                                                      float* __restrict__ hout, int N) {
    __shared__ float sT[ROWS * 128];
    const int nb = blockIdx.x * ROWS;
    constexpr int NGRP = THREADS / 32;

    // ---- phase 1: aggregate ROWS rows into LDS ----
    {
        const int gp = threadIdx.x >> 5;
        const int l32 = threadIdx.x & 31;
        const int c = l32 << 2;
        const int p0 = permc(c);
        for (int s = gp; s < ROWS; s += NGRP) {
            int node = nb + s;
            if (node >= N) continue;
            float di = dinv[node];
            float s2 = di * di;
            float4 t0 = *(const float4*)&hin[(size_t)node * D + c];
            float4 acc;
            acc.x = s2 * t0.x; acc.y = s2 * t0.y;
            acc.z = s2 * t0.z; acc.w = s2 * t0.w;

            int s0 = rowst[node];
            int cnt = deg[node];
            int j = 0;
            for (; j + 4 <= cnt; j += 4) {
                int2 e0 = csr[s0 + j + 0];
                int2 e1 = csr[s0 + j + 1];
                int2 e2 = csr[s0 + j + 2];
                int2 e3 = csr[s0 + j + 3];
                float4 r0 = *(const float4*)&hin[(size_t)e0.x * D + c];
                float4 r1 = *(const float4*)&hin[(size_t)e1.x * D + c];
                float4 r2 = *(const float4*)&hin[(size_t)e2.x * D + c];
                float4 r3 = *(const float4*)&hin[(size_t)e3.x * D + c];
                float w0 = __int_as_float(e0.y), w1 = __int_as_float(e1.y);
                float w2 = __int_as_float(e2.y), w3 = __int_as_float(e3.y);
                acc.x = fmaf(w0, r0.x, acc.x); acc.y = fmaf(w0, r0.y, acc.y);
                acc.z = fmaf(w0, r0.z, acc.z); acc.w = fmaf(w0, r0.w, acc.w);
                acc.x = fmaf(w1, r1.x, acc.x); acc.y = fmaf(w1, r1.y, acc.y);
                acc.z = fmaf(w1, r1.z, acc.z); acc.w = fmaf(w1, r1.w, acc.w);
                acc.x = fmaf(w2, r2.x, acc.x); acc.y = fmaf(w2, r2.y, acc.y);
                acc.z = fmaf(w2, r2.z, acc.z); acc.w = fmaf(w2, r2.w, acc.w);
                acc.x = fmaf(w3, r3.x, acc.x); acc.y = fmaf(w3, r3.y, acc.y);
                acc.z = fmaf(w3, r3.z, acc.z); acc.w = fmaf(w3, r3.w, acc.w);
            }
            for (; j < cnt; ++j) {
                int2 e = csr[s0 + j];
                float4 r = *(const float4*)&hin[(size_t)e.x * D + c];
                float w = __int_as_float(e.y);
                acc.x = fmaf(w, r.x, acc.x); acc.y = fmaf(w, r.y, acc.y);
                acc.z = fmaf(w, r.z, acc.z); acc.w = fmaf(w, r.w, acc.w);
            }
            // MFMA-permuted + bank-swizzled LDS store
            int idx = s * 128 + (p0 ^ ((s & 7) << 2));
            *(float4*)&sT[idx] = acc;
        }
    }
    __syncthreads();

    // ---- phase 2: split-bf16 MFMA ----
    constexpr int WAVES = THREADS / 64;
    constexpr int WR = (ROWS / 16 < WAVES) ? ROWS / 16 : WAVES;  // row tiles
    constexpr int CG = WAVES / WR;        // col groups (waves per row tile)
    constexpr int NTW = NTT / CG;         // col tiles per wave
    const int w = threadIdx.x >> 6;
    const int lane = threadIdx.x & 63;
    const int q = lane & 15, g = lane >> 4;
    const int rtile = w % WR;
    const int cg = w / WR;
    const int rloc = rtile * 16 + q;
    const int sw = (q & 7) << 2;

    v4f acc[NTW];
#pragma unroll
    for (int nt = 0; nt < NTW; ++nt) acc[nt] = (v4f)0.f;

    const float* rp = &sT[rloc * 128];

#pragma unroll
    for (int ks = 0; ks < 4; ++ks) {
        int o = ks * 32 + g * 8;
        float4 fa = *(const float4*)&rp[o ^ sw];
        float4 fb = *(const float4*)&rp[(o + 4) ^ sw];
        v8s ah, al;
        {
            unsigned short h_, l_;
            f2hl(fa.x, h_, l_); ah[0] = (short)h_; al[0] = (short)l_;
            f2hl(fa.y, h_, l_); ah[1] = (short)h_; al[1] = (short)l_;
            f2hl(fa.z, h_, l_); ah[2] = (short)h_; al[2] = (short)l_;
            f2hl(fa.w, h_, l_); ah[3] = (short)h_; al[3] = (short)l_;
            f2hl(fb.x, h_, l_); ah[4] = (short)h_; al[4] = (short)l_;
            f2hl(fb.y, h_, l_); ah[5] = (short)h_; al[5] = (short)l_;
            f2hl(fb.z, h_, l_); ah[6] = (short)h_; al[6] = (short)l_;
            f2hl(fb.w, h_, l_); ah[7] = (short)h_; al[7] = (short)l_;
        }
        const unsigned int* wk = wf + ((size_t)(ks * NTT + cg * NTW) * 64 + lane) * 8;
#pragma unroll
        for (int nt = 0; nt < NTW; ++nt) {
            v8s wh = *(const v8s*)(wk + nt * 512);
            v8s wl = *(const v8s*)(wk + nt * 512 + 4);
            acc[nt] = __builtin_amdgcn_mfma_f32_16x16x32_bf16(ah, wh, acc[nt], 0, 0, 0);
            acc[nt] = __builtin_amdgcn_mfma_f32_16x16x32_bf16(al, wh, acc[nt], 0, 0, 0);
            acc[nt] = __builtin_amdgcn_mfma_f32_16x16x32_bf16(ah, wl, acc[nt], 0, 0, 0);
        }
    }

    // ---- epilogue: bias (+ReLU), store. C/D layout: col = q, row = 4g + i ----
    const int growb = nb + rtile * 16 + 4 * g;
#pragma unroll
    for (int nt = 0; nt < NTW; ++nt) {
        int col = (cg * NTW + nt) * 16 + q;
        float bv = bias[col];
#pragma unroll
        for (int i = 0; i < 4; ++i) {
            int grow = growb + i;
            if (grow < N) {
                float v = acc[nt][i] + bv;
                if (RELU) v = fmaxf(v, 0.f);
                hout[(size_t)grow * OSTRIDE + col] = v;
            }
        }
    }
}

// ---------------- launch ----------------

extern "C" void kernel_launch(void* const* d_in, const int* in_sizes, int n_in,
                              void* d_out, int out_size, void* d_ws, size_t ws_size,
                              hipStream_t stream) {
    const float* x  = (const float*)d_in[0];
    const int*   ei = (const int*)d_in[1];
    const float* Ws = (const float*)d_in[2];
    const float* bs = (const float*)d_in[3];
    const float* Wo = (const float*)d_in[4];
    const float* bo = (const float*)d_in[5];
    float* out = (float*)d_out;

    const int N = in_sizes[0] / D;     // 100000
    const int E = in_sizes[1] / 2;     // 600000
    const int* src = ei;
    const int* dst = ei + E;

    // workspace layout (~109.4 MB)
    float* H0     = (float*)d_ws;                     // N*128 fp32 ping
    float* H1     = H0 + (size_t)N * D;               // N*128 fp32 pong
    int*   deg    = (int*)(H1 + (size_t)N * D);
    int*   cursor = deg + N;
    int*   rowst  = cursor + N;
    float* dinv   = (float*)(rowst + N);
    int*   bsums  = (int*)(dinv + N);
    int2*  csr    = (int2*)(bsums + 1024);
    unsigned int* wfrag  = (unsigned int*)(csr + E);  // 9 * 16384 uints (576 KB)
    unsigned int* wofrag = wfrag + 9 * 16384;         // 2048 uints (8 KB)

    const int NB = (N + 1023) / 1024;

    hipMemsetAsync(deg, 0, (size_t)2 * N * sizeof(int), stream);  // deg + cursor
    k_count<<<(E + 255) / 256, 256, 0, stream>>>(dst, deg, E);
    k_blocksum<<<NB, 256, 0, stream>>>(deg, bsums, N);
    k_scanbsums<<<1, 256, 0, stream>>>(bsums, NB);
    k_scan2<<<NB, 256, 0, stream>>>(deg, bsums, rowst, dinv, N);
    k_fill<<<(E + 255) / 256, 256, 0, stream>>>(src, dst, rowst, cursor, dinv, csr, E);

    k_wconv<<<288, 64, 0, stream>>>(Ws, wfrag);
    k_woconv<<<4, 64, 0, stream>>>(Wo, wofrag);

    const float* hin = x;
    float* hout = H0;
    const int gblk16 = (N + 15) / 16;
    for (int l = 0; l < 9; ++l) {
        k_fused<128, 16, 8, 1, 128><<<gblk16, 128, 0, stream>>>(hin, csr, rowst, deg,
                                                                dinv,
                                                                wfrag + (size_t)l * 16384,
                                                                bs + (size_t)l * D,
                                                                hout, N);
        hin = hout;
        hout = (hout == H0) ? H1 : H0;
    }
    const int gblk64 = (N + 63) / 64;
    k_fused<256, 64, 1, 0, 16><<<gblk64, 256, 0, stream>>>(hin, csr, rowst, deg, dinv,
                                                           wofrag, bo, out, N);
}